// Round 1
// baseline (176.650 us; speedup 1.0000x reference)
//
#include <hip/hip_runtime.h>
#include <hip/hip_bf16.h>
#include <math.h>

typedef __bf16 bf16_t;
typedef __bf16 bf16x8 __attribute__((ext_vector_type(8)));
typedef __bf16 bf16x4 __attribute__((ext_vector_type(4)));
typedef float  f32x4  __attribute__((ext_vector_type(4)));

#define NBATCH 4
#define SB     4096
#define BS     (NBATCH*SB)   // 16384 total rows
#define DIM    256

// ---------------- helpers ----------------

__device__ __forceinline__ float softplus_f(float x) {
  // log(1+exp(x)) = max(x,0) + log1p(exp(-|x|))  (matches jax.nn.softplus)
  return fmaxf(x, 0.0f) + log1pf(__expf(-fabsf(x)));
}

__device__ __forceinline__ void gload_lds16(const void* g, void* l) {
  __builtin_amdgcn_global_load_lds(
      (const __attribute__((address_space(1))) void*)g,
      (__attribute__((address_space(3))) void*)l,
      16, 0, 0);
}

__device__ __forceinline__ void cvt4(const float* __restrict__ s,
                                     bf16_t* __restrict__ d, int qi) {
  const float4 v = *(const float4*)(s + (size_t)qi * 4);
  bf16x4 o;
  o[0] = (bf16_t)v.x; o[1] = (bf16_t)v.y; o[2] = (bf16_t)v.z; o[3] = (bf16_t)v.w;
  *(bf16x4*)(d + (size_t)qi * 4) = o;
}

// ---------------- prep kernels ----------------

// Convert x, Wq, Wk to bf16; zero the fp32 M accumulator.
__global__ void prep_convert(const float* __restrict__ x,
                             const float* __restrict__ Wq,
                             const float* __restrict__ Wk,
                             bf16_t* __restrict__ xb,
                             bf16_t* __restrict__ Wqb,
                             bf16_t* __restrict__ Wkb,
                             float* __restrict__ MT) {
  const int QX = BS * DIM / 4;          // 1048576 quads
  const int QW = DIM * DIM / 4;         // 16384 quads
  const int QM = NBATCH * DIM * DIM / 4; // 65536 quads
  const int total = QX + 2 * QW + QM;
  for (int qi = blockIdx.x * blockDim.x + threadIdx.x; qi < total;
       qi += gridDim.x * blockDim.x) {
    if (qi < QX)               cvt4(x,  xb,  qi);
    else if (qi < QX + QW)     cvt4(Wq, Wqb, qi - QX);
    else if (qi < QX + 2 * QW) cvt4(Wk, Wkb, qi - QX - QW);
    else {
      float4 z; z.x = z.y = z.z = z.w = 0.0f;
      *(float4*)(MT + (size_t)(qi - QX - 2 * QW) * 4) = z;
    }
  }
}

// Wvo = Wo @ Wv  (fold output projection into v), bvo = Wo @ bv.
__global__ void prep_wvo(const float* __restrict__ Wv,
                         const float* __restrict__ Wo,
                         const float* __restrict__ bv,
                         bf16_t* __restrict__ Wvob,
                         float* __restrict__ bvo) {
  const int j = blockIdx.x;   // output row 0..255
  const int t = threadIdx.x;  // output col 0..255
  float acc = 0.0f;
  for (int i = 0; i < DIM; ++i)
    acc = fmaf(Wo[j * DIM + i], Wv[i * DIM + t], acc);
  Wvob[(size_t)j * DIM + t] = (bf16_t)acc;
  if (t == 0) {
    float a = 0.0f;
    for (int i = 0; i < DIM; ++i) a = fmaf(Wo[j * DIM + i], bv[i], a);
    bvo[j] = a;
  }
}

// ---------------- shared 128x128 staged-GEMM core ----------------
// C(128x128) = A[r0..r0+128, 0:256] * B[c0..c0+128, 0:256]^T, both bf16
// row-major with row stride 256 elements (512B). 4 waves in 2x2 grid,
// each wave computes a 64x64 sub-tile as 4x4 mfma_f32_16x16x32_bf16 frags.
// LDS: 64KB (A tile 32KB + B tile 32KB per 128-wide K step, 2 steps).
// XOR swizzle: physical 16B chunk = logical chunk ^ (row & 7); applied to
// the GLOBAL source address at stage time (LDS dest stays linear for
// global_load_lds) and to the ds_read address at use time.
__device__ __forceinline__ void gemm128_core(
    const bf16_t* __restrict__ Abase,   // &A[r0][0]
    const bf16_t* __restrict__ Bbase,   // &B[c0][0]
    char* smem, int tid, f32x4 acc[4][4]) {
  const int lane = tid & 63;
  const int w = tid >> 6;
  const int wr = w & 1, wc = w >> 1;
  #pragma unroll
  for (int kk = 0; kk < 2; ++kk) {
    const char* asrc = (const char*)Abase + kk * 256;  // 128 cols * 2B
    const char* bsrc = (const char*)Bbase + kk * 256;
    #pragma unroll
    for (int it = 0; it < 8; ++it) {
      const int L = it * 256 + tid;           // 16B chunk id, 0..2047
      const int row = L >> 4;                 // tile row 0..127
      const int lch = (L & 15) ^ (row & 7);   // logical chunk (inverse swz)
      char* la = smem + (size_t)(it * 256 + w * 64) * 16;  // wave-uniform
      char* lb = la + 32768;
      gload_lds16(asrc + (size_t)row * 512 + lch * 16, la);
      gload_lds16(bsrc + (size_t)row * 512 + lch * 16, lb);
    }
    __syncthreads();
    #pragma unroll
    for (int ks = 0; ks < 4; ++ks) {
      const int kb = ks * 64 + ((lane >> 4) << 4);  // byte offset in row
      bf16x8 af[4], bg[4];
      #pragma unroll
      for (int mi = 0; mi < 4; ++mi) {
        const int row = wr * 64 + mi * 16 + (lane & 15);
        const int ch = (kb >> 4) ^ (row & 7);
        af[mi] = *(const bf16x8*)(smem + (size_t)row * 256 + ch * 16);
      }
      #pragma unroll
      for (int ni = 0; ni < 4; ++ni) {
        const int row = wc * 64 + ni * 16 + (lane & 15);
        const int ch = (kb >> 4) ^ (row & 7);
        bg[ni] = *(const bf16x8*)(smem + 32768 + (size_t)row * 256 + ch * 16);
      }
      #pragma unroll
      for (int mi = 0; mi < 4; ++mi)
        #pragma unroll
        for (int ni = 0; ni < 4; ++ni)
          acc[mi][ni] = __builtin_amdgcn_mfma_f32_16x16x32_bf16(
              af[mi], bg[ni], acc[mi][ni], 0, 0, 0);
    }
    __syncthreads();
  }
}

// ---------------- QKV projection ----------------
// grid (128 row-tiles, 2 col-halves, 3 mats). mode 0: q=softplus(x Wq^T+bq)
// stored row-major; mode 1: k=softplus(..) stored transposed [b][d][s];
// mode 2: v'=x Wvo^T + bvo stored transposed.
__global__ __launch_bounds__(256) void qkv_gemm(
    const bf16_t* __restrict__ xb,
    const bf16_t* __restrict__ Wqb,
    const bf16_t* __restrict__ Wkb,
    const bf16_t* __restrict__ Wvob,
    const float* __restrict__ bq,
    const float* __restrict__ bk,
    const float* __restrict__ bvo,
    bf16_t* __restrict__ qo,
    bf16_t* __restrict__ kT,
    bf16_t* __restrict__ vT) {
  __shared__ __align__(16) char smem[65536];
  const int mode = blockIdx.z;
  const int r0 = blockIdx.x * 128;
  const int c0 = blockIdx.y * 128;
  const bf16_t* W   = (mode == 0) ? Wqb : (mode == 1) ? Wkb : Wvob;
  const float* bias = (mode == 0) ? bq  : (mode == 1) ? bk  : bvo;
  const int tid = threadIdx.x;
  const int lane = tid & 63;
  const int w = tid >> 6;
  const int wr = w & 1, wc = w >> 1;

  f32x4 zero = {0.0f, 0.0f, 0.0f, 0.0f};
  f32x4 acc[4][4];
  #pragma unroll
  for (int i = 0; i < 4; ++i)
    #pragma unroll
    for (int j = 0; j < 4; ++j) acc[i][j] = zero;

  gemm128_core(xb + (size_t)r0 * DIM, W + (size_t)c0 * DIM, smem, tid, acc);

  const int batch = r0 >> 12;  // 4096 rows per batch
  #pragma unroll
  for (int ni = 0; ni < 4; ++ni) {
    const int col = c0 + wc * 64 + ni * 16 + (lane & 15);
    const float bb = bias[col];
    #pragma unroll
    for (int mi = 0; mi < 4; ++mi) {
      const int srow = r0 + wr * 64 + mi * 16 + ((lane >> 4) << 2);
      f32x4 v = acc[mi][ni];
      float o0 = v[0] + bb, o1 = v[1] + bb, o2 = v[2] + bb, o3 = v[3] + bb;
      if (mode < 2) {
        o0 = softplus_f(o0); o1 = softplus_f(o1);
        o2 = softplus_f(o2); o3 = softplus_f(o3);
      }
      if (mode == 0) {
        qo[(size_t)(srow + 0) * DIM + col] = (bf16_t)o0;
        qo[(size_t)(srow + 1) * DIM + col] = (bf16_t)o1;
        qo[(size_t)(srow + 2) * DIM + col] = (bf16_t)o2;
        qo[(size_t)(srow + 3) * DIM + col] = (bf16_t)o3;
      } else {
        bf16_t* dst = (mode == 1) ? kT : vT;
        const int sin = srow & (SB - 1);
        bf16x4 p;
        p[0] = (bf16_t)o0; p[1] = (bf16_t)o1; p[2] = (bf16_t)o2; p[3] = (bf16_t)o3;
        *(bf16x4*)(dst + (size_t)batch * DIM * SB + (size_t)col * SB + sin) = p;
      }
    }
  }
}

// ---------------- M = v'^T k  (per batch, split-K over S, atomics) -------
// Computes NB[b][j][d] = sum_s v'[s][j] * k[s][d]   (fp32 accumulate).
// A = vT rows (j, K=s contiguous), B = kT rows (d, K=s contiguous).
// grid (4 quadrants, 32 s-chunks of 128, 4 batches), 4 waves/block.
__global__ __launch_bounds__(256) void m_gemm(
    const bf16_t* __restrict__ kT,
    const bf16_t* __restrict__ vT,
    float* __restrict__ MT) {
  const int quad = blockIdx.x;
  const int sc   = blockIdx.y;
  const int b    = blockIdx.z;
  const int tid = threadIdx.x;
  const int lane = tid & 63;
  const int w = tid >> 6;
  const int wr = w & 1, wc = w >> 1;
  const int j0 = (quad & 1) * 128 + wr * 64;
  const int d0 = (quad >> 1) * 128 + wc * 64;
  const bf16_t* vb = vT + (size_t)b * DIM * SB;
  const bf16_t* kb = kT + (size_t)b * DIM * SB;

  f32x4 zero = {0.0f, 0.0f, 0.0f, 0.0f};
  f32x4 acc[4][4];
  #pragma unroll
  for (int i = 0; i < 4; ++i)
    #pragma unroll
    for (int j = 0; j < 4; ++j) acc[i][j] = zero;

  const int svec = sc * 128 + ((lane >> 4) << 3);
  #pragma unroll
  for (int it = 0; it < 4; ++it) {
    const int s = svec + it * 32;
    bf16x8 af[4], bg[4];
    #pragma unroll
    for (int mi = 0; mi < 4; ++mi)
      af[mi] = *(const bf16x8*)(vb + (size_t)(j0 + mi * 16 + (lane & 15)) * SB + s);
    #pragma unroll
    for (int ni = 0; ni < 4; ++ni)
      bg[ni] = *(const bf16x8*)(kb + (size_t)(d0 + ni * 16 + (lane & 15)) * SB + s);
    #pragma unroll
    for (int mi = 0; mi < 4; ++mi)
      #pragma unroll
      for (int ni = 0; ni < 4; ++ni)
        acc[mi][ni] = __builtin_amdgcn_mfma_f32_16x16x32_bf16(
            af[mi], bg[ni], acc[mi][ni], 0, 0, 0);
  }

  float* o = MT + (size_t)b * DIM * DIM;
  #pragma unroll
  for (int mi = 0; mi < 4; ++mi) {
    const int row = j0 + mi * 16 + ((lane >> 4) << 2);
    #pragma unroll
    for (int ni = 0; ni < 4; ++ni) {
      const int col = d0 + ni * 16 + (lane & 15);
      #pragma unroll
      for (int r = 0; r < 4; ++r)
        atomicAdd(o + (size_t)(row + r) * DIM + col, acc[mi][ni][r]);
    }
  }
}

// ---------------- NB fp32 -> bf16 ----------------
__global__ void conv_nt(const float* __restrict__ MT, bf16_t* __restrict__ NTb) {
  const int qi = blockIdx.x * blockDim.x + threadIdx.x;
  if (qi < NBATCH * DIM * DIM / 4) {
    const float4 v = *(const float4*)(MT + (size_t)qi * 4);
    bf16x4 o;
    o[0] = (bf16_t)v.x; o[1] = (bf16_t)v.y; o[2] = (bf16_t)v.z; o[3] = (bf16_t)v.w;
    *(bf16x4*)(NTb + (size_t)qi * 4) = o;
  }
}

// ---------------- out = q @ NB^T + bo (fp32 store) ----------------
__global__ __launch_bounds__(256) void out_gemm(
    const bf16_t* __restrict__ qo,
    const bf16_t* __restrict__ NTb,
    const float* __restrict__ bo,
    float* __restrict__ out) {
  __shared__ __align__(16) char smem[65536];
  const int r0 = blockIdx.x * 128;
  const int c0 = blockIdx.y * 128;
  const int batch = r0 >> 12;
  const int tid = threadIdx.x;
  const int lane = tid & 63;
  const int w = tid >> 6;
  const int wr = w & 1, wc = w >> 1;

  f32x4 zero = {0.0f, 0.0f, 0.0f, 0.0f};
  f32x4 acc[4][4];
  #pragma unroll
  for (int i = 0; i < 4; ++i)
    #pragma unroll
    for (int j = 0; j < 4; ++j) acc[i][j] = zero;

  gemm128_core(qo + (size_t)r0 * DIM,
               NTb + (size_t)batch * DIM * DIM + (size_t)c0 * DIM,
               smem, tid, acc);

  #pragma unroll
  for (int ni = 0; ni < 4; ++ni) {
    const int col = c0 + wc * 64 + ni * 16 + (lane & 15);
    const float bb = bo[col];
    #pragma unroll
    for (int mi = 0; mi < 4; ++mi) {
      const int srow = r0 + wr * 64 + mi * 16 + ((lane >> 4) << 2);
      f32x4 v = acc[mi][ni];
      #pragma unroll
      for (int r = 0; r < 4; ++r)
        out[(size_t)(srow + r) * DIM + col] = v[r] + bb;
    }
  }
}

// ---------------- launch ----------------

extern "C" void kernel_launch(void* const* d_in, const int* in_sizes, int n_in,
                              void* d_out, int out_size, void* d_ws, size_t ws_size,
                              hipStream_t stream) {
  const float* x  = (const float*)d_in[0];
  const float* Wq = (const float*)d_in[1];
  const float* bq = (const float*)d_in[2];
  const float* Wk = (const float*)d_in[3];
  const float* bk = (const float*)d_in[4];
  const float* Wv = (const float*)d_in[5];
  const float* bv = (const float*)d_in[6];
  const float* Wo = (const float*)d_in[7];
  const float* bo = (const float*)d_in[8];
  float* out = (float*)d_out;

  char* ws = (char*)d_ws;
  bf16_t* xb   = (bf16_t*)(ws);                 //  8,388,608 B
  bf16_t* qo   = (bf16_t*)(ws + 8388608);       //  8,388,608 B
  bf16_t* kT   = (bf16_t*)(ws + 16777216);      //  8,388,608 B
  bf16_t* vT   = (bf16_t*)(ws + 25165824);      //  8,388,608 B
  bf16_t* Wqb  = (bf16_t*)(ws + 33554432);      //    131,072 B
  bf16_t* Wkb  = (bf16_t*)(ws + 33685504);      //    131,072 B
  bf16_t* Wvob = (bf16_t*)(ws + 33816576);      //    131,072 B
  float*  bvo  = (float*)(ws + 33947648);       //      1,024 B
  float*  MT   = (float*)(ws + 33948672);       //  1,048,576 B
  bf16_t* NTb  = (bf16_t*)(ws + 34997248);      //    524,288 B  (end 35,521,536)

  prep_convert<<<1024, 256, 0, stream>>>(x, Wq, Wk, xb, Wqb, Wkb, MT);
  prep_wvo<<<256, 256, 0, stream>>>(Wv, Wo, bv, Wvob, bvo);
  qkv_gemm<<<dim3(128, 2, 3), 256, 0, stream>>>(xb, Wqb, Wkb, Wvob,
                                                bq, bk, bvo, qo, kT, vT);
  m_gemm<<<dim3(4, 32, 4), 256, 0, stream>>>(kT, vT, MT);
  conv_nt<<<256, 256, 0, stream>>>(MT, NTb);
  out_gemm<<<dim3(128, 2), 256, 0, stream>>>(qo, NTb, bo, out);
}

// Round 3
// 149.615 us; speedup vs baseline: 1.1807x; 1.1807x over previous
//
#include <hip/hip_runtime.h>
#include <hip/hip_bf16.h>
#include <math.h>

typedef __bf16 bf16_t;
typedef __bf16 bf16x8 __attribute__((ext_vector_type(8)));
typedef __bf16 bf16x4 __attribute__((ext_vector_type(4)));
typedef float  f32x4  __attribute__((ext_vector_type(4)));

#define NBATCH 4
#define SB     4096
#define BS     (NBATCH*SB)   // 16384 total rows
#define DIM    256
#define NCHUNK 16            // split-K chunks for M = v'^T k

// ---------------- helpers ----------------

__device__ __forceinline__ float softplus_f(float x) {
  // log(1+exp(x)) = max(x,0) + log1p(exp(-|x|))  (matches jax.nn.softplus)
  return fmaxf(x, 0.0f) + log1pf(__expf(-fabsf(x)));
}

__device__ __forceinline__ void gload_lds16(const void* g, void* l) {
  __builtin_amdgcn_global_load_lds(
      (const __attribute__((address_space(1))) void*)g,
      (__attribute__((address_space(3))) void*)l,
      16, 0, 0);
}

__device__ __forceinline__ void cvt4(const float* __restrict__ s,
                                     bf16_t* __restrict__ d, int qi) {
  const float4 v = *(const float4*)(s + (size_t)qi * 4);
  bf16x4 o;
  o[0] = (bf16_t)v.x; o[1] = (bf16_t)v.y; o[2] = (bf16_t)v.z; o[3] = (bf16_t)v.w;
  *(bf16x4*)(d + (size_t)qi * 4) = o;
}

// ---------------- prep: convert x/Wq/Wk to bf16 + Wvo=Wo@Wv fold ---------
// blocks 0..1023: grid-stride bf16 conversion. blocks 1024..1279: Wvo row j.
__global__ void prep_all(const float* __restrict__ x,
                         const float* __restrict__ Wq,
                         const float* __restrict__ Wk,
                         const float* __restrict__ Wv,
                         const float* __restrict__ Wo,
                         const float* __restrict__ bv,
                         bf16_t* __restrict__ xb,
                         bf16_t* __restrict__ Wqb,
                         bf16_t* __restrict__ Wkb,
                         bf16_t* __restrict__ Wvob,
                         float* __restrict__ bvo) {
  if (blockIdx.x < 1024) {
    const int QX = BS * DIM / 4;   // 1048576 quads
    const int QW = DIM * DIM / 4;  // 16384 quads
    const int total = QX + 2 * QW;
    for (int qi = blockIdx.x * blockDim.x + threadIdx.x; qi < total;
         qi += 1024 * blockDim.x) {
      if (qi < QX)           cvt4(x,  xb,  qi);
      else if (qi < QX + QW) cvt4(Wq, Wqb, qi - QX);
      else                   cvt4(Wk, Wkb, qi - QX - QW);
    }
  } else {
    const int j = blockIdx.x - 1024;  // output row 0..255
    const int t = threadIdx.x;        // output col 0..255
    float acc = 0.0f;
    for (int i = 0; i < DIM; ++i)
      acc = fmaf(Wo[j * DIM + i], Wv[i * DIM + t], acc);
    Wvob[(size_t)j * DIM + t] = (bf16_t)acc;
    if (t == 0) {
      float a = 0.0f;
      for (int i = 0; i < DIM; ++i) a = fmaf(Wo[j * DIM + i], bv[i], a);
      bvo[j] = a;
    }
  }
}

// ---------------- shared 128x128 staged-GEMM core ----------------
// C(128x128) = A[r0..r0+128, 0:256] * B[c0..c0+128, 0:256]^T, both bf16
// row-major with row stride 256 elements (512B). 4 waves in 2x2 grid,
// each wave computes a 64x64 sub-tile as 4x4 mfma_f32_16x16x32_bf16 frags.
// XOR swizzle: physical 16B chunk = logical chunk ^ (row & 7); applied to
// the GLOBAL source address at stage time (LDS dest stays linear for
// global_load_lds) and to the ds_read address at use time.
__device__ __forceinline__ void gemm128_core(
    const bf16_t* __restrict__ Abase,   // &A[r0][0]
    const bf16_t* __restrict__ Bbase,   // &B[c0][0]
    char* smem, int tid, f32x4 acc[4][4]) {
  const int lane = tid & 63;
  const int w = tid >> 6;
  const int wr = w & 1, wc = w >> 1;
  #pragma unroll
  for (int kk = 0; kk < 2; ++kk) {
    const char* asrc = (const char*)Abase + kk * 256;  // 128 cols * 2B
    const char* bsrc = (const char*)Bbase + kk * 256;
    #pragma unroll
    for (int it = 0; it < 8; ++it) {
      const int L = it * 256 + tid;           // 16B chunk id, 0..2047
      const int row = L >> 4;                 // tile row 0..127
      const int lch = (L & 15) ^ (row & 7);   // logical chunk (inverse swz)
      char* la = smem + (size_t)(it * 256 + w * 64) * 16;  // wave-uniform
      char* lb = la + 32768;
      gload_lds16(asrc + (size_t)row * 512 + lch * 16, la);
      gload_lds16(bsrc + (size_t)row * 512 + lch * 16, lb);
    }
    __syncthreads();
    #pragma unroll
    for (int ks = 0; ks < 4; ++ks) {
      const int kb = ks * 64 + ((lane >> 4) << 4);  // byte offset in row
      bf16x8 af[4], bg[4];
      #pragma unroll
      for (int mi = 0; mi < 4; ++mi) {
        const int row = wr * 64 + mi * 16 + (lane & 15);
        const int ch = (kb >> 4) ^ (row & 7);
        af[mi] = *(const bf16x8*)(smem + (size_t)row * 256 + ch * 16);
      }
      #pragma unroll
      for (int ni = 0; ni < 4; ++ni) {
        const int row = wc * 64 + ni * 16 + (lane & 15);
        const int ch = (kb >> 4) ^ (row & 7);
        bg[ni] = *(const bf16x8*)(smem + 32768 + (size_t)row * 256 + ch * 16);
      }
      #pragma unroll
      for (int mi = 0; mi < 4; ++mi)
        #pragma unroll
        for (int ni = 0; ni < 4; ++ni)
          acc[mi][ni] = __builtin_amdgcn_mfma_f32_16x16x32_bf16(
              af[mi], bg[ni], acc[mi][ni], 0, 0, 0);
    }
    __syncthreads();
  }
}

// ---------------- QKV projection ----------------
// grid (128 row-tiles, 2 col-halves, 3 mats). mode 0: q=softplus(x Wq^T+bq)
// stored row-major; mode 1: k=softplus(..) stored transposed [b][d][s];
// mode 2: v'=x Wvo^T + bvo stored transposed.
__global__ __launch_bounds__(256) void qkv_gemm(
    const bf16_t* __restrict__ xb,
    const bf16_t* __restrict__ Wqb,
    const bf16_t* __restrict__ Wkb,
    const bf16_t* __restrict__ Wvob,
    const float* __restrict__ bq,
    const float* __restrict__ bk,
    const float* __restrict__ bvo,
    bf16_t* __restrict__ qo,
    bf16_t* __restrict__ kT,
    bf16_t* __restrict__ vT) {
  __shared__ __align__(16) char smem[65536];
  const int mode = blockIdx.z;
  const int r0 = blockIdx.x * 128;
  const int c0 = blockIdx.y * 128;
  const bf16_t* W   = (mode == 0) ? Wqb : (mode == 1) ? Wkb : Wvob;
  const float* bias = (mode == 0) ? bq  : (mode == 1) ? bk  : bvo;
  const int tid = threadIdx.x;
  const int lane = tid & 63;
  const int w = tid >> 6;
  const int wr = w & 1, wc = w >> 1;

  f32x4 zero = {0.0f, 0.0f, 0.0f, 0.0f};
  f32x4 acc[4][4];
  #pragma unroll
  for (int i = 0; i < 4; ++i)
    #pragma unroll
    for (int j = 0; j < 4; ++j) acc[i][j] = zero;

  gemm128_core(xb + (size_t)r0 * DIM, W + (size_t)c0 * DIM, smem, tid, acc);

  const int batch = r0 >> 12;  // 4096 rows per batch
  #pragma unroll
  for (int ni = 0; ni < 4; ++ni) {
    const int col = c0 + wc * 64 + ni * 16 + (lane & 15);
    const float bb = bias[col];
    #pragma unroll
    for (int mi = 0; mi < 4; ++mi) {
      const int srow = r0 + wr * 64 + mi * 16 + ((lane >> 4) << 2);
      f32x4 v = acc[mi][ni];
      float o0 = v[0] + bb, o1 = v[1] + bb, o2 = v[2] + bb, o3 = v[3] + bb;
      if (mode < 2) {
        o0 = softplus_f(o0); o1 = softplus_f(o1);
        o2 = softplus_f(o2); o3 = softplus_f(o3);
      }
      if (mode == 0) {
        qo[(size_t)(srow + 0) * DIM + col] = (bf16_t)o0;
        qo[(size_t)(srow + 1) * DIM + col] = (bf16_t)o1;
        qo[(size_t)(srow + 2) * DIM + col] = (bf16_t)o2;
        qo[(size_t)(srow + 3) * DIM + col] = (bf16_t)o3;
      } else {
        bf16_t* dst = (mode == 1) ? kT : vT;
        const int sin = srow & (SB - 1);
        bf16x4 p;
        p[0] = (bf16_t)o0; p[1] = (bf16_t)o1; p[2] = (bf16_t)o2; p[3] = (bf16_t)o3;
        *(bf16x4*)(dst + (size_t)batch * DIM * SB + (size_t)col * SB + sin) = p;
      }
    }
  }
}

// ---------------- M partials = v'^T k  (per batch, split-K, no atomics) --
// MTp[sc][b][j][d] += over s in chunk sc: v'[s][j] * k[s][d] (fp32 stores).
// grid (4 quadrants, NCHUNK s-chunks of 256, 4 batches), 4 waves/block.
__global__ __launch_bounds__(256) void m_gemm(
    const bf16_t* __restrict__ kT,
    const bf16_t* __restrict__ vT,
    float* __restrict__ MTp) {
  const int quad = blockIdx.x;
  const int sc   = blockIdx.y;
  const int b    = blockIdx.z;
  const int tid = threadIdx.x;
  const int lane = tid & 63;
  const int w = tid >> 6;
  const int wr = w & 1, wc = w >> 1;
  const int j0 = (quad & 1) * 128 + wr * 64;
  const int d0 = (quad >> 1) * 128 + wc * 64;
  const bf16_t* vb = vT + (size_t)b * DIM * SB;
  const bf16_t* kb = kT + (size_t)b * DIM * SB;

  f32x4 zero = {0.0f, 0.0f, 0.0f, 0.0f};
  f32x4 acc[4][4];
  #pragma unroll
  for (int i = 0; i < 4; ++i)
    #pragma unroll
    for (int j = 0; j < 4; ++j) acc[i][j] = zero;

  const int svec = sc * 256 + ((lane >> 4) << 3);
  #pragma unroll
  for (int it = 0; it < 8; ++it) {
    const int s = svec + it * 32;
    bf16x8 af[4], bg[4];
    #pragma unroll
    for (int mi = 0; mi < 4; ++mi)
      af[mi] = *(const bf16x8*)(vb + (size_t)(j0 + mi * 16 + (lane & 15)) * SB + s);
    #pragma unroll
    for (int ni = 0; ni < 4; ++ni)
      bg[ni] = *(const bf16x8*)(kb + (size_t)(d0 + ni * 16 + (lane & 15)) * SB + s);
    #pragma unroll
    for (int mi = 0; mi < 4; ++mi)
      #pragma unroll
      for (int ni = 0; ni < 4; ++ni)
        acc[mi][ni] = __builtin_amdgcn_mfma_f32_16x16x32_bf16(
            af[mi], bg[ni], acc[mi][ni], 0, 0, 0);
  }

  float* o = MTp + ((size_t)sc * NBATCH + b) * DIM * DIM;
  #pragma unroll
  for (int mi = 0; mi < 4; ++mi) {
    const int row = j0 + mi * 16 + ((lane >> 4) << 2);
    #pragma unroll
    for (int ni = 0; ni < 4; ++ni) {
      const int col = d0 + ni * 16 + (lane & 15);
      #pragma unroll
      for (int r = 0; r < 4; ++r)
        o[(size_t)(row + r) * DIM + col] = acc[mi][ni][r];
    }
  }
}

// ---------------- reduce partials -> bf16 NTb ----------------
__global__ void reduce_nt(const float* __restrict__ MTp,
                          bf16_t* __restrict__ NTb) {
  const int qi = blockIdx.x * blockDim.x + threadIdx.x;  // 0..65535
  f32x4 s = {0.0f, 0.0f, 0.0f, 0.0f};
  #pragma unroll
  for (int c = 0; c < NCHUNK; ++c) {
    const float4 v =
        *(const float4*)(MTp + (size_t)c * NBATCH * DIM * DIM + (size_t)qi * 4);
    s[0] += v.x; s[1] += v.y; s[2] += v.z; s[3] += v.w;
  }
  bf16x4 o;
  o[0] = (bf16_t)s[0]; o[1] = (bf16_t)s[1];
  o[2] = (bf16_t)s[2]; o[3] = (bf16_t)s[3];
  *(bf16x4*)(NTb + (size_t)qi * 4) = o;
}

// ---------------- out = q @ NB^T + bo (fp32 store) ----------------
__global__ __launch_bounds__(256) void out_gemm(
    const bf16_t* __restrict__ qo,
    const bf16_t* __restrict__ NTb,
    const float* __restrict__ bo,
    float* __restrict__ out) {
  __shared__ __align__(16) char smem[65536];
  const int r0 = blockIdx.x * 128;
  const int c0 = blockIdx.y * 128;
  const int batch = r0 >> 12;
  const int tid = threadIdx.x;
  const int lane = tid & 63;
  const int w = tid >> 6;
  const int wr = w & 1, wc = w >> 1;

  f32x4 zero = {0.0f, 0.0f, 0.0f, 0.0f};
  f32x4 acc[4][4];
  #pragma unroll
  for (int i = 0; i < 4; ++i)
    #pragma unroll
    for (int j = 0; j < 4; ++j) acc[i][j] = zero;

  gemm128_core(qo + (size_t)r0 * DIM,
               NTb + (size_t)batch * DIM * DIM + (size_t)c0 * DIM,
               smem, tid, acc);

  #pragma unroll
  for (int ni = 0; ni < 4; ++ni) {
    const int col = c0 + wc * 64 + ni * 16 + (lane & 15);
    const float bb = bo[col];
    #pragma unroll
    for (int mi = 0; mi < 4; ++mi) {
      const int srow = r0 + wr * 64 + mi * 16 + ((lane >> 4) << 2);
      f32x4 v = acc[mi][ni];
      #pragma unroll
      for (int r = 0; r < 4; ++r)
        out[(size_t)(srow + r) * DIM + col] = v[r] + bb;
    }
  }
}

// ---------------- launch ----------------

extern "C" void kernel_launch(void* const* d_in, const int* in_sizes, int n_in,
                              void* d_out, int out_size, void* d_ws, size_t ws_size,
                              hipStream_t stream) {
  const float* x  = (const float*)d_in[0];
  const float* Wq = (const float*)d_in[1];
  const float* bq = (const float*)d_in[2];
  const float* Wk = (const float*)d_in[3];
  const float* bk = (const float*)d_in[4];
  const float* Wv = (const float*)d_in[5];
  const float* bv = (const float*)d_in[6];
  const float* Wo = (const float*)d_in[7];
  const float* bo = (const float*)d_in[8];
  float* out = (float*)d_out;

  char* ws = (char*)d_ws;
  bf16_t* xb   = (bf16_t*)(ws);                 //  8,388,608 B
  bf16_t* qo   = (bf16_t*)(ws + 8388608);       //  8,388,608 B
  bf16_t* kT   = (bf16_t*)(ws + 16777216);      //  8,388,608 B
  bf16_t* vT   = (bf16_t*)(ws + 25165824);      //  8,388,608 B
  bf16_t* Wqb  = (bf16_t*)(ws + 33554432);      //    131,072 B
  bf16_t* Wkb  = (bf16_t*)(ws + 33685504);      //    131,072 B
  bf16_t* Wvob = (bf16_t*)(ws + 33816576);      //    131,072 B
  float*  bvo  = (float*)(ws + 33947648);       //      1,024 B
  bf16_t* NTb  = (bf16_t*)(ws + 33948672);      //    524,288 B
  float*  MTp  = (float*)(ws + 34472960);       // 16,777,216 B (end ~51.3MB)

  prep_all<<<1280, 256, 0, stream>>>(x, Wq, Wk, Wv, Wo, bv,
                                     xb, Wqb, Wkb, Wvob, bvo);
  qkv_gemm<<<dim3(128, 2, 3), 256, 0, stream>>>(xb, Wqb, Wkb, Wvob,
                                                bq, bk, bvo, qo, kT, vT);
  m_gemm<<<dim3(4, NCHUNK, 4), 256, 0, stream>>>(kT, vT, MTp);
  reduce_nt<<<256, 256, 0, stream>>>(MTp, NTb);
  out_gemm<<<dim3(128, 2), 256, 0, stream>>>(qo, NTb, bo, out);
}